// Round 5
// baseline (97.454 us; speedup 1.0000x reference)
//
#include <hip/hip_runtime.h>
#include <math.h>

#define BLK  256
#define DD   128
#define NN   15
#define NL   16
#define OC   16
#define WSTR 260   // per-leaf LDS stride (floats)
#define XSTR 17    // x-tile row stride (floats)

__global__ __launch_bounds__(BLK, 4)
void dts_fused5(const float* __restrict__ x, const float* __restrict__ Wn,
                const float* __restrict__ bn, const float* __restrict__ Wl,
                const float* __restrict__ bl, float* __restrict__ out, int B)
{
    // uShared: phase 1 = WnT [15][128] (1920 floats); phase 3 = x-tile [256][17] / out un-permute
    __shared__ __align__(16) float uShared[BLK * XSTR];   // 17408 B
    __shared__ __align__(16) float sWl[NL * WSTR];        // 16640 B
    __shared__ float sBn[NN];
    __shared__ __align__(16) float sBl[NL * OC];
    __shared__ int sPerm[BLK];
    __shared__ int sLeaf[BLK];
    __shared__ int sBins[NL];
    __shared__ int sStarts[NL];

    const int t = threadIdx.x;
    const int row = blockIdx.x * BLK + t;
    const int rowL = (row < B) ? row : 0;
    const float4* xr = reinterpret_cast<const float4*>(x + (size_t)rowL * DD);

    // ---- stage WnT, bn, bl ----
    for (int i = t; i < NN * DD; i += BLK) {
        int n = i >> 7, d = i & 127;
        uShared[i] = Wn[d * NN + n];          // Wn is [D][NN]
    }
    if (t < NN) sBn[t] = bn[t];
    for (int i = t; i < NL * OC; i += BLK) sBl[i] = bl[i];
    if (t < NL) sBins[t] = 0;
    __syncthreads();

    // ---- phase 1: 15 node dots, x streamed (uniform LDS reads = broadcast) ----
    float acc[NN];
    #pragma unroll
    for (int n = 0; n < NN; ++n) acc[n] = 0.f;
    #pragma unroll 4
    for (int q = 0; q < DD / 4; ++q) {
        const float4 xv = xr[q];
        #pragma unroll
        for (int n = 0; n < NN; ++n) {
            const float4 w = *(const float4*)&uShared[n * DD + q * 4];
            acc[n] = fmaf(xv.w, w.w, fmaf(xv.z, w.z,
                     fmaf(xv.y, w.y, fmaf(xv.x, w.x, acc[n]))));
        }
    }
    #pragma unroll
    for (int n = 0; n < NN; ++n) acc[n] += sBn[n];

    // ---- tree expand + argmax (leaf bits MSB-first, bit0 = left = +) ----
    float L2a[4], L3a[8], L4a[16];
    {
        float p = acc[0], m = -acc[0];
        L2a[0] = p + acc[1]; L2a[1] = p - acc[1];
        L2a[2] = m + acc[2]; L2a[3] = m - acc[2];
        #pragma unroll
        for (int i = 0; i < 4; ++i) { L3a[2*i] = L2a[i] + acc[3+i]; L3a[2*i+1] = L2a[i] - acc[3+i]; }
        #pragma unroll
        for (int i = 0; i < 8; ++i) { L4a[2*i] = L3a[i] + acc[7+i]; L4a[2*i+1] = L3a[i] - acc[7+i]; }
    }
    int best = 0; float bv = L4a[0];
    #pragma unroll
    for (int l = 1; l < NL; ++l) if (L4a[l] > bv) { bv = L4a[l]; best = l; }

    // ---- counting sort: group rows by leaf so waves get ~uniform leaf -> LDS broadcast ----
    int rank = atomicAdd(&sBins[best], 1);
    __syncthreads();       // also: all phase-1 uShared reads complete
    if (t == 0) {
        int s = 0;
        #pragma unroll
        for (int l = 0; l < NL; ++l) { sStarts[l] = s; s += sBins[l]; }
    }
    __syncthreads();
    {
        int slot = sStarts[best] + rank;
        sPerm[slot] = t;
        sLeaf[slot] = best;
    }
    __syncthreads();

    const int r    = sPerm[t];     // row (in-block) this thread computes
    const int leaf = sLeaf[t];
    const float* wb = &sWl[leaf * WSTR];
    float* xmine = &uShared[t * XSTR];
    const float* xperm = &uShared[r * XSTR];

    // ---- out accumulators from bias (broadcast within sorted wave) ----
    float4 o0, o1, o2, o3;
    {
        const float4* blv = reinterpret_cast<const float4*>(&sBl[leaf * OC]);
        o0 = blv[0]; o1 = blv[1]; o2 = blv[2]; o3 = blv[3];
    }

    // ---- Wl staging geometry: thread t stages leaf t>>4, dim-block t&15 ----
    const float* gw = Wl + ((size_t)(t >> 4) * (DD * OC) + (t & 15) * 16);
    const int stofs = (t >> 4) * WSTR + (t & 15) * 16;

    // ---- phase 3: 8 chunks of 16 dims ----
    #pragma unroll 1
    for (int c = 0; c < 8; ++c) {
        // transient staging loads (L2/L3-hot): Wl chunk + own x chunk
        const float* g_ = gw + c * 256;
        const float4 s0 = *(const float4*)(g_);
        const float4 s1 = *(const float4*)(g_ + 4);
        const float4 s2 = *(const float4*)(g_ + 8);
        const float4 s3 = *(const float4*)(g_ + 12);
        const float4 xc0 = xr[c * 4 + 0];
        const float4 xc1 = xr[c * 4 + 1];
        const float4 xc2 = xr[c * 4 + 2];
        const float4 xc3 = xr[c * 4 + 3];

        __syncthreads();   // previous chunk's sWl/x-tile readers done
        {
            float* d_ = &sWl[stofs];
            *(float4*)(d_)      = s0; *(float4*)(d_ + 4)  = s1;
            *(float4*)(d_ + 8)  = s2; *(float4*)(d_ + 12) = s3;
            *(float4*)(xmine)       = xc0;
            *(float4*)(xmine + 4)   = xc1;
            *(float4*)(xmine + 8)   = xc2;
            *(float4*)(xmine + 12)  = xc3;
        }
        __syncthreads();   // chunk c visible

        // permuted x chunk from LDS (stride-17 rows -> conflict-light)
        const float4 a0 = *(const float4*)(xperm);
        const float4 a1 = *(const float4*)(xperm + 4);
        const float4 a2 = *(const float4*)(xperm + 8);
        const float4 a3 = *(const float4*)(xperm + 12);

        const float* wc = wb;   // sorted wave: 1-3 unique leaves -> broadcast reads
        #define KSTEP(xv, k) { \
            const float4 w0 = *(const float4*)&wc[(k) * 16 + 0];  \
            const float4 w1 = *(const float4*)&wc[(k) * 16 + 4];  \
            const float4 w2 = *(const float4*)&wc[(k) * 16 + 8];  \
            const float4 w3 = *(const float4*)&wc[(k) * 16 + 12]; \
            o0.x = fmaf((xv), w0.x, o0.x); o0.y = fmaf((xv), w0.y, o0.y); \
            o0.z = fmaf((xv), w0.z, o0.z); o0.w = fmaf((xv), w0.w, o0.w); \
            o1.x = fmaf((xv), w1.x, o1.x); o1.y = fmaf((xv), w1.y, o1.y); \
            o1.z = fmaf((xv), w1.z, o1.z); o1.w = fmaf((xv), w1.w, o1.w); \
            o2.x = fmaf((xv), w2.x, o2.x); o2.y = fmaf((xv), w2.y, o2.y); \
            o2.z = fmaf((xv), w2.z, o2.z); o2.w = fmaf((xv), w2.w, o2.w); \
            o3.x = fmaf((xv), w3.x, o3.x); o3.y = fmaf((xv), w3.y, o3.y); \
            o3.z = fmaf((xv), w3.z, o3.z); o3.w = fmaf((xv), w3.w, o3.w); }
        KSTEP(a0.x,  0) KSTEP(a0.y,  1) KSTEP(a0.z,  2) KSTEP(a0.w,  3)
        KSTEP(a1.x,  4) KSTEP(a1.y,  5) KSTEP(a1.z,  6) KSTEP(a1.w,  7)
        KSTEP(a2.x,  8) KSTEP(a2.y,  9) KSTEP(a2.z, 10) KSTEP(a2.w, 11)
        KSTEP(a3.x, 12) KSTEP(a3.y, 13) KSTEP(a3.z, 14) KSTEP(a3.w, 15)
        #undef KSTEP
    }

    // ---- un-permute outputs through LDS, then coalesced store ----
    __syncthreads();   // last chunk's x-tile reads done
    {
        float* d_ = &uShared[r * XSTR];
        *(float4*)(d_)      = o0; *(float4*)(d_ + 4)  = o1;
        *(float4*)(d_ + 8)  = o2; *(float4*)(d_ + 12) = o3;
    }
    __syncthreads();

    if (row < B) {
        const float* so = &uShared[t * XSTR];
        const float4 m0 = *(const float4*)(so);
        const float4 m1 = *(const float4*)(so + 4);
        const float4 s0 = *(const float4*)(so + 8);
        const float4 s1 = *(const float4*)(so + 12);

        size_t ob = (size_t)row * 8;
        *reinterpret_cast<float4*>(&out[ob])     = m0;
        *reinterpret_cast<float4*>(&out[ob + 4]) = m1;

        // log_std = -1.5 + 3.5*tanh(v); tanh(v) = 1 - 2/(e^{2v}+1)
        float4 r0, r1;
        #define SQ(v) (-1.5f + 3.5f * (1.f - 2.f / (__expf(2.f * (v)) + 1.f)))
        r0.x = SQ(s0.x); r0.y = SQ(s0.y); r0.z = SQ(s0.z); r0.w = SQ(s0.w);
        r1.x = SQ(s1.x); r1.y = SQ(s1.y); r1.z = SQ(s1.z); r1.w = SQ(s1.w);
        #undef SQ
        size_t ob2 = (size_t)B * 8 + ob;
        *reinterpret_cast<float4*>(&out[ob2])     = r0;
        *reinterpret_cast<float4*>(&out[ob2 + 4]) = r1;
    }
}

extern "C" void kernel_launch(void* const* d_in, const int* in_sizes, int n_in,
                              void* d_out, int out_size, void* d_ws, size_t ws_size,
                              hipStream_t stream)
{
    const float* x  = (const float*)d_in[0];
    const float* Wn = (const float*)d_in[1];
    const float* bn = (const float*)d_in[2];
    const float* Wl = (const float*)d_in[3];
    const float* bl = (const float*)d_in[4];
    float* out = (float*)d_out;

    const int B = in_sizes[0] / DD;              // 262144
    const int blocks = (B + BLK - 1) / BLK;      // 1024

    hipLaunchKernelGGL(dts_fused5, dim3(blocks), dim3(BLK), 0, stream,
                       x, Wn, bn, Wl, bl, out, B);
}

// Round 6
// 89.973 us; speedup vs baseline: 1.0831x; 1.0831x over previous
//
#include <hip/hip_runtime.h>
#include <math.h>

#define BLK  256
#define DD   128
#define NN   15
#define NL   16
#define OC   16
#define XROWS 272    // 256 slots + 16 pad rows (ragged-tile overread)
#define XSTR  40     // bf16 per x-lds row: 32 data + 8 pad = 80 B (16B-aligned, 2-way banks)
#define WSTR  40     // bf16 per Wl-lds row (per out-channel): 32 k + 8 pad
#define MAXT  32
#define TPW   8      // max tiles per wave (ceil(31/4))

typedef __attribute__((ext_vector_type(8))) short short8v;
typedef __attribute__((ext_vector_type(4))) float f32x4;

__device__ inline unsigned pack_bf16(float a, float b) {
    unsigned ua = __float_as_uint(a); ua = (ua + 0x7FFFu + ((ua >> 16) & 1u)) >> 16;
    unsigned ub = __float_as_uint(b); ub = (ub + 0x7FFFu + ((ub >> 16) & 1u)) >> 16;
    return ua | (ub << 16);   // low 16 = a (lower address / even k)
}

__global__ __launch_bounds__(BLK, 3)
void dts_fused6(const float* __restrict__ x, const float* __restrict__ Wn,
                const float* __restrict__ bn, const float* __restrict__ Wl,
                const float* __restrict__ bl, float* __restrict__ out, int B)
{
    __shared__ __align__(16) float sWnT[NN * DD];              // 7680 B (phase 1)
    __shared__ __align__(16) unsigned short sX[XROWS * XSTR];  // 21760 B, sorted x chunk (bf16)
    __shared__ __align__(16) unsigned short sWT[NL * OC * WSTR]; // 20480 B, Wl chunk [leaf][o][k] bf16
    __shared__ float sBn[NN];
    __shared__ __align__(16) float sBl[NL * OC];
    __shared__ int sPerm[BLK];
    __shared__ int sBins[NL];
    __shared__ int sStarts[NL];
    __shared__ int sTleaf[MAXT];
    __shared__ int sTm0[MAXT];
    __shared__ int sTend[MAXT];
    __shared__ int sNT;

    const int t  = threadIdx.x;
    const int wv = t >> 6;          // wave id 0..3
    const int lo = t & 15;          // lane%16
    const int grp = (t >> 4) & 3;   // (lane%64)>>4
    const int rowBase = blockIdx.x * BLK;
    const int row = rowBase + t;
    const int rowL = (row < B) ? row : 0;
    const float4* xr = reinterpret_cast<const float4*>(x + (size_t)rowL * DD);

    // ---- stage WnT, bn, bl ----
    for (int i = t; i < NN * DD; i += BLK) {
        int n = i >> 7, d = i & 127;
        sWnT[i] = Wn[d * NN + n];          // Wn is [D][NN]
    }
    if (t < NN) sBn[t] = bn[t];
    for (int i = t; i < NL * OC; i += BLK) sBl[i] = bl[i];
    if (t < NL) sBins[t] = 0;
    __syncthreads();

    // ---- phase 1: 15 node dots in exact f32 (argmax safety) ----
    float acc1[NN];
    #pragma unroll
    for (int n = 0; n < NN; ++n) acc1[n] = 0.f;
    #pragma unroll 4
    for (int q = 0; q < DD / 4; ++q) {
        const float4 xv = xr[q];
        #pragma unroll
        for (int n = 0; n < NN; ++n) {
            const float4 w = *(const float4*)&sWnT[n * DD + q * 4];
            acc1[n] = fmaf(xv.w, w.w, fmaf(xv.z, w.z,
                      fmaf(xv.y, w.y, fmaf(xv.x, w.x, acc1[n]))));
        }
    }
    #pragma unroll
    for (int n = 0; n < NN; ++n) acc1[n] += sBn[n];

    // ---- tree expand + argmax ----
    float L2a[4], L3a[8], L4a[16];
    {
        float p = acc1[0], m = -acc1[0];
        L2a[0] = p + acc1[1]; L2a[1] = p - acc1[1];
        L2a[2] = m + acc1[2]; L2a[3] = m - acc1[2];
        #pragma unroll
        for (int i = 0; i < 4; ++i) { L3a[2*i] = L2a[i] + acc1[3+i]; L3a[2*i+1] = L2a[i] - acc1[3+i]; }
        #pragma unroll
        for (int i = 0; i < 8; ++i) { L4a[2*i] = L3a[i] + acc1[7+i]; L4a[2*i+1] = L3a[i] - acc1[7+i]; }
    }
    int best = 0; float bv = L4a[0];
    #pragma unroll
    for (int l = 1; l < NL; ++l) if (L4a[l] > bv) { bv = L4a[l]; best = l; }

    // ---- counting sort by leaf + tile list ----
    int rank = atomicAdd(&sBins[best], 1);
    __syncthreads();
    if (t == 0) {
        int s = 0, nt = 0;
        #pragma unroll
        for (int l = 0; l < NL; ++l) {
            sStarts[l] = s;
            int c = sBins[l];
            for (int m0 = s; m0 < s + c; m0 += 16) {
                sTleaf[nt] = l; sTm0[nt] = m0; sTend[nt] = s + c; ++nt;
            }
            s += c;
        }
        sNT = nt;
    }
    __syncthreads();
    const int slot = sStarts[best] + rank;   // this thread's row goes to x_lds[slot]
    sPerm[slot] = t;
    __syncthreads();
    const int nT = sNT;

    // ---- per-wave tile registers (static-indexed) ----
    int tleaf[TPW], tm0[TPW], tend[TPW], aoff[TPW], boff[TPW];
    #pragma unroll
    for (int i = 0; i < TPW; ++i) {
        int tid = wv + i * 4;
        bool v = tid < nT;
        tleaf[i] = v ? sTleaf[tid] : 0;
        tm0[i]   = v ? sTm0[tid]   : 0;
        tend[i]  = v ? sTend[tid]  : 0;
        aoff[i]  = (tm0[i] + lo) * XSTR + grp * 8;               // bf16 units
        boff[i]  = tleaf[i] * (OC * WSTR) + lo * WSTR + grp * 8; // bf16 units
    }
    f32x4 accm[TPW];
    #pragma unroll
    for (int i = 0; i < TPW; ++i) accm[i] = (f32x4){0.f, 0.f, 0.f, 0.f};

    // staging geometry: x -> own row to slot; Wl: leaf=t>>4, k-pair kk=t&15
    const int kk = t & 15;
    const int wleaf = t >> 4;
    unsigned short* xdst = &sX[slot * XSTR];
    unsigned short* wdst = &sWT[wleaf * (OC * WSTR) + kk * 2];

    // ---- phase 3: 4 k-chunks of 32, MFMA ----
    #pragma unroll 1
    for (int c = 0; c < 4; ++c) {
        // transient global loads (L2/L3-hot)
        const float4 x0 = xr[c*8+0], x1 = xr[c*8+1], x2 = xr[c*8+2], x3 = xr[c*8+3];
        const float4 x4 = xr[c*8+4], x5 = xr[c*8+5], x6 = xr[c*8+6], x7 = xr[c*8+7];
        const float* gp = Wl + (size_t)wleaf * (DD * OC) + (size_t)(c * 32 + kk * 2) * OC;
        const float4 wa0 = *(const float4*)(gp);      const float4 wa1 = *(const float4*)(gp + 4);
        const float4 wa2 = *(const float4*)(gp + 8);  const float4 wa3 = *(const float4*)(gp + 12);
        const float4 wb0 = *(const float4*)(gp + 16); const float4 wb1 = *(const float4*)(gp + 20);
        const float4 wb2 = *(const float4*)(gp + 24); const float4 wb3 = *(const float4*)(gp + 28);

        __syncthreads();   // previous chunk's frag readers done
        {
            // x row (32 bf16) -> sorted slot
            uint4* xd = (uint4*)xdst;
            xd[0] = make_uint4(pack_bf16(x0.x,x0.y), pack_bf16(x0.z,x0.w),
                               pack_bf16(x1.x,x1.y), pack_bf16(x1.z,x1.w));
            xd[1] = make_uint4(pack_bf16(x2.x,x2.y), pack_bf16(x2.z,x2.w),
                               pack_bf16(x3.x,x3.y), pack_bf16(x3.z,x3.w));
            xd[2] = make_uint4(pack_bf16(x4.x,x4.y), pack_bf16(x4.z,x4.w),
                               pack_bf16(x5.x,x5.y), pack_bf16(x5.z,x5.w));
            xd[3] = make_uint4(pack_bf16(x6.x,x6.y), pack_bf16(x6.z,x6.w),
                               pack_bf16(x7.x,x7.y), pack_bf16(x7.z,x7.w));
            // Wl: two k-rows (k=even, k+1) -> transposed [o][k] (b32 = k,k+1 pair per o)
            *(unsigned*)&wdst[ 0*WSTR] = pack_bf16(wa0.x, wb0.x);
            *(unsigned*)&wdst[ 1*WSTR] = pack_bf16(wa0.y, wb0.y);
            *(unsigned*)&wdst[ 2*WSTR] = pack_bf16(wa0.z, wb0.z);
            *(unsigned*)&wdst[ 3*WSTR] = pack_bf16(wa0.w, wb0.w);
            *(unsigned*)&wdst[ 4*WSTR] = pack_bf16(wa1.x, wb1.x);
            *(unsigned*)&wdst[ 5*WSTR] = pack_bf16(wa1.y, wb1.y);
            *(unsigned*)&wdst[ 6*WSTR] = pack_bf16(wa1.z, wb1.z);
            *(unsigned*)&wdst[ 7*WSTR] = pack_bf16(wa1.w, wb1.w);
            *(unsigned*)&wdst[ 8*WSTR] = pack_bf16(wa2.x, wb2.x);
            *(unsigned*)&wdst[ 9*WSTR] = pack_bf16(wa2.y, wb2.y);
            *(unsigned*)&wdst[10*WSTR] = pack_bf16(wa2.z, wb2.z);
            *(unsigned*)&wdst[11*WSTR] = pack_bf16(wa2.w, wb2.w);
            *(unsigned*)&wdst[12*WSTR] = pack_bf16(wa3.x, wb3.x);
            *(unsigned*)&wdst[13*WSTR] = pack_bf16(wa3.y, wb3.y);
            *(unsigned*)&wdst[14*WSTR] = pack_bf16(wa3.z, wb3.z);
            *(unsigned*)&wdst[15*WSTR] = pack_bf16(wa3.w, wb3.w);
        }
        __syncthreads();   // chunk visible

        #pragma unroll
        for (int i = 0; i < TPW; ++i) {
            if (wv + i * 4 < nT) {   // wave-uniform branch
                short8v af = *(const short8v*)&sX[aoff[i]];
                short8v bf = *(const short8v*)&sWT[boff[i]];
                accm[i] = __builtin_amdgcn_mfma_f32_16x16x32_bf16(af, bf, accm[i], 0, 0, 0);
            }
        }
    }

    // ---- epilogue: bias + tanh-squash + store (D: col=lane&15, row=(lane>>4)*4+j) ----
    #pragma unroll
    for (int i = 0; i < TPW; ++i) {
        if (wv + i * 4 < nT) {
            const float bias = sBl[tleaf[i] * OC + lo];
            #pragma unroll
            for (int j = 0; j < 4; ++j) {
                const int sl = tm0[i] + grp * 4 + j;
                if (sl < tend[i]) {
                    const int r = sPerm[sl];
                    const size_t grow = (size_t)rowBase + r;
                    const float v = accm[i][j] + bias;
                    if (lo < 8) {
                        out[grow * 8 + lo] = v;
                    } else {
                        // log_std = -1.5 + 3.5*tanh(v); tanh = 1 - 2/(e^{2v}+1)
                        out[(size_t)B * 8 + grow * 8 + (lo - 8)] =
                            -1.5f + 3.5f * (1.f - 2.f / (__expf(2.f * v) + 1.f));
                    }
                }
            }
        }
    }
}

extern "C" void kernel_launch(void* const* d_in, const int* in_sizes, int n_in,
                              void* d_out, int out_size, void* d_ws, size_t ws_size,
                              hipStream_t stream)
{
    const float* x  = (const float*)d_in[0];
    const float* Wn = (const float*)d_in[1];
    const float* bn = (const float*)d_in[2];
    const float* Wl = (const float*)d_in[3];
    const float* bl = (const float*)d_in[4];
    float* out = (float*)d_out;

    const int B = in_sizes[0] / DD;              // 262144
    const int blocks = (B + BLK - 1) / BLK;      // 1024

    hipLaunchKernelGGL(dts_fused6, dim3(blocks), dim3(BLK), 0, stream,
                       x, Wn, bn, Wl, bl, out, B);
}